// Round 5
// baseline (636.975 us; speedup 1.0000x reference)
//
#include <hip/hip_runtime.h>
#include <hip/hip_bf16.h>

#define NN 50000
#define NE 800000
#define D 128

#define RPB 98            // rows per bucket
#define NB 511            // ceil(NN/RPB)
#define CAP 2560          // record capacity per bucket (mean 1566)
#define TILE 4096         // edges per bin block
#define NBIN 196          // ceil(NE/TILE)
#define STRIDE 132        // LDS acc row stride (floats): breaks bank conflicts
#define AROWS 112         // padded rows (7 mtiles x 16)

#define CAST_BLKS 3125    // 800000 uint4-casts of x
#define PACK_BLKS 8

// ws layout in dwords
#define XH_OFF   0                   // x_h bf16: 3,200,000 dwords
#define WF_OFF   3200000             // Wf: 8192 dwords
#define CUR_OFF  3208192             // 512 cursors
#define REC_OFF  3208704             // records: 512*CAP int2 = 2,621,440 dwords

typedef short bf16x8 __attribute__((ext_vector_type(8)));
typedef float f32x4 __attribute__((ext_vector_type(4)));

__device__ inline unsigned short f2bf_u(float f) {
    __hip_bfloat16 h = __float2bfloat16(f);   // RNE
    return __builtin_bit_cast(unsigned short, h);
}
__device__ inline unsigned pack2(float a, float b) {
    return (unsigned)f2bf_u(a) | ((unsigned)f2bf_u(b) << 16);
}

// ---------------------------------------------------------------------------
// 1) fused: cast x->bf16 | pack W into MFMA-B-frag order | zero bucket cursors
// ---------------------------------------------------------------------------
__global__ __launch_bounds__(256) void cast_pack_zero_kernel(
    const float* __restrict__ x, const float* __restrict__ W,
    unsigned* __restrict__ x_h4, unsigned short* __restrict__ Wf,
    int* __restrict__ cursor)
{
    int b = blockIdx.x;
    int t = threadIdx.x;
    if (b < CAST_BLKS) {
        int idx = b * 256 + t;                 // [0, 800000)
        const float4* x4 = (const float4*)x;
        float4 v0 = x4[idx * 2];
        float4 v1 = x4[idx * 2 + 1];
        uint4 o;
        o.x = pack2(v0.x, v0.y);
        o.y = pack2(v0.z, v0.w);
        o.z = pack2(v1.x, v1.y);
        o.w = pack2(v1.z, v1.w);
        ((uint4*)x_h4)[idx] = o;
    } else if (b < CAST_BLKS + PACK_BLKS) {
        // Wf[(nt*4+c)*64+lane] : element j -> W[c*32+(lane>>4)*8+j][nt*16+(lane&15)]
        int flat = (b - CAST_BLKS) * 256 + t;  // [0, 2048)
        int lane = flat & 63;
        int c    = (flat >> 6) & 3;
        int nt   = flat >> 8;
        int col  = nt * 16 + (lane & 15);
        int kb   = c * 32 + (lane >> 4) * 8;
        unsigned d[4];
        #pragma unroll
        for (int jj = 0; jj < 4; ++jj) {
            float a  = W[(kb + 2 * jj) * D + col];
            float bb = W[(kb + 2 * jj + 1) * D + col];
            d[jj] = pack2(a, bb);
        }
        uint4 o; o.x = d[0]; o.y = d[1]; o.z = d[2]; o.w = d[3];
        ((uint4*)Wf)[flat] = o;
    } else {
        cursor[t] = 0;
        cursor[t + 256] = 0;
    }
}

// ---------------------------------------------------------------------------
// 2) bin edges into 511 coarse buckets (98 rows each) with LDS staging so
//    global record writes are clustered runs, not random 8B scatters.
//    record: {.x = (row<<16)|col, .y = w bits}
// ---------------------------------------------------------------------------
__global__ __launch_bounds__(512) void bin_kernel(
    const int* __restrict__ erow, const int* __restrict__ ecol,
    const float* __restrict__ ew, int* __restrict__ cursor,
    int2* __restrict__ recs)
{
    __shared__ int  lhist[512];   // counts, then rank cursor
    __shared__ int  lexcl[512];   // scan workspace, then exclusive prefix
    __shared__ int  lbase[512];   // global base per bucket
    __shared__ int2 stag[TILE];   // staged records

    int t = threadIdx.x;
    int base = blockIdx.x * TILE;
    int cnt = NE - base; if (cnt > TILE) cnt = TILE;

    lhist[t] = 0;
    __syncthreads();

    // load up to 8 edges (two int4 groups), coalesced
    int4 r[2], c[2]; float4 w[2]; bool val[2];
    #pragma unroll
    for (int g = 0; g < 2; ++g) {
        int i4 = (base >> 2) + t + g * 512;
        val[g] = (i4 * 4) < NE && (i4 * 4) < (base + TILE);
        if (val[g]) {
            r[g] = ((const int4*)erow)[i4];
            c[g] = ((const int4*)ecol)[i4];
            w[g] = ((const float4*)ew)[i4];
        }
    }
    // histogram
    #pragma unroll
    for (int g = 0; g < 2; ++g) {
        if (val[g]) {
            atomicAdd(&lhist[(unsigned)r[g].x / RPB], 1);
            atomicAdd(&lhist[(unsigned)r[g].y / RPB], 1);
            atomicAdd(&lhist[(unsigned)r[g].z / RPB], 1);
            atomicAdd(&lhist[(unsigned)r[g].w / RPB], 1);
        }
    }
    __syncthreads();

    // exclusive scan (Hillis-Steele over 512)
    int c0 = lhist[t];
    lexcl[t] = c0;
    __syncthreads();
    for (int off = 1; off < 512; off <<= 1) {
        int v = (t >= off) ? lexcl[t - off] : 0;
        __syncthreads();
        lexcl[t] += v;
        __syncthreads();
    }
    int excl = lexcl[t] - c0;
    int gb = (c0 > 0) ? atomicAdd(&cursor[t], c0) : 0;
    lexcl[t] = excl;    // keep exclusive prefix for decode
    lbase[t] = gb;
    lhist[t] = excl;    // rank cursor
    __syncthreads();

    // scatter into LDS staging at local rank
    #pragma unroll
    for (int g = 0; g < 2; ++g) {
        if (val[g]) {
            int rr[4] = {r[g].x, r[g].y, r[g].z, r[g].w};
            int cc[4] = {c[g].x, c[g].y, c[g].z, c[g].w};
            float wwv[4] = {w[g].x, w[g].y, w[g].z, w[g].w};
            #pragma unroll
            for (int j = 0; j < 4; ++j) {
                int bk = (unsigned)rr[j] / RPB;
                int rank = atomicAdd(&lhist[bk], 1);
                int2 rec;
                rec.x = (rr[j] << 16) | cc[j];
                rec.y = __float_as_int(wwv[j]);
                stag[rank] = rec;
            }
        }
    }
    __syncthreads();

    // write out: consecutive slots -> contiguous runs per bucket
    #pragma unroll
    for (int k = 0; k < 8; ++k) {
        int i = t + k * 512;
        if (i < cnt) {
            int2 rec = stag[i];
            int row = ((unsigned)rec.x) >> 16;
            int bk = (unsigned)row / RPB;
            size_t g = (size_t)bk * CAP + lbase[bk] + (i - lexcl[bk]);
            recs[g] = rec;
        }
    }
}

// ---------------------------------------------------------------------------
// 3) per-bucket: LDS fp32 accumulate (ds_add_f32) + in-place MFMA GEMM + bias
//    block = 512 thr (8 waves); bucket = 98 rows; LDS acc 112x132 fp32.
// ---------------------------------------------------------------------------
__global__ __launch_bounds__(512) void agg_gemm_kernel(
    const unsigned short* __restrict__ x_h, const int2* __restrict__ recs,
    const int* __restrict__ cursor, const unsigned short* __restrict__ Wf,
    const float* __restrict__ bias, float* __restrict__ out)
{
    __shared__ float sacc[AROWS * STRIDE];   // 59136 B

    int t = threadIdx.x;
    int b = blockIdx.x;
    int cnt = cursor[b];

    for (int i = t; i < AROWS * STRIDE; i += 512) sacc[i] = 0.f;
    __syncthreads();

    int wave = t >> 6, lane = t & 63;
    const int2* my = recs + (size_t)b * CAP;
    int chunk = (cnt + 7) >> 3;
    int s0 = wave * chunk;
    int s1 = s0 + chunk; if (s1 > cnt) s1 = cnt;
    const unsigned* xw = (const unsigned*)x_h;   // row = 64 dwords
    int rb = b * RPB;

    int i = s0;
    for (; i + 4 <= s1; i += 4) {
        int2 r0 = my[i], r1 = my[i + 1], r2 = my[i + 2], r3 = my[i + 3];
        unsigned v0 = xw[(size_t)(r0.x & 0xffff) * 64 + lane];
        unsigned v1 = xw[(size_t)(r1.x & 0xffff) * 64 + lane];
        unsigned v2 = xw[(size_t)(r2.x & 0xffff) * 64 + lane];
        unsigned v3 = xw[(size_t)(r3.x & 0xffff) * 64 + lane];
        int2 rr[4] = {r0, r1, r2, r3};
        unsigned vv[4] = {v0, v1, v2, v3};
        #pragma unroll
        for (int j = 0; j < 4; ++j) {
            float w = __int_as_float(rr[j].y);
            int rl = (((unsigned)rr[j].x) >> 16) - rb;
            float lo = __int_as_float((int)(vv[j] << 16));
            float hi = __int_as_float((int)(vv[j] & 0xffff0000u));
            float* dst = &sacc[rl * STRIDE + lane * 2];
            atomicAdd(dst, w * lo);
            atomicAdd(dst + 1, w * hi);
        }
    }
    for (; i < s1; ++i) {
        int2 r = my[i];
        unsigned v = xw[(size_t)(r.x & 0xffff) * 64 + lane];
        float w = __int_as_float(r.y);
        int rl = (((unsigned)r.x) >> 16) - rb;
        float lo = __int_as_float((int)(v << 16));
        float hi = __int_as_float((int)(v & 0xffff0000u));
        float* dst = &sacc[rl * STRIDE + lane * 2];
        atomicAdd(dst, w * lo);
        atomicAdd(dst + 1, w * hi);
    }
    __syncthreads();

    // GEMM: out[rb..rb+97][:] = bf16(sacc) @ W + bias; wave = ntile
    int m = lane & 15, quad = lane >> 4;
    const bf16x8* bp = (const bf16x8*)Wf;
    bf16x8 bfr[4];
    #pragma unroll
    for (int cc = 0; cc < 4; ++cc) bfr[cc] = bp[(wave * 4 + cc) * 64 + lane];
    float bcol = bias[wave * 16 + m];

    for (int mt = 0; mt < 7; ++mt) {
        f32x4 acc = {0.f, 0.f, 0.f, 0.f};
        #pragma unroll
        for (int cc = 0; cc < 4; ++cc) {
            const float* ap = &sacc[(mt * 16 + m) * STRIDE + cc * 32 + quad * 8];
            float4 f0 = *(const float4*)ap;
            float4 f1 = *(const float4*)(ap + 4);
            uint4 u;
            u.x = pack2(f0.x, f0.y);
            u.y = pack2(f0.z, f0.w);
            u.z = pack2(f1.x, f1.y);
            u.w = pack2(f1.z, f1.w);
            bf16x8 afr = __builtin_bit_cast(bf16x8, u);
            acc = __builtin_amdgcn_mfma_f32_16x16x32_bf16(afr, bfr[cc], acc, 0, 0, 0);
        }
        #pragma unroll
        for (int rgi = 0; rgi < 4; ++rgi) {
            int lr = mt * 16 + quad * 4 + rgi;
            int grow = rb + lr;
            if (lr < RPB && grow < NN)
                out[(size_t)grow * D + wave * 16 + m] = acc[rgi] + bcol;
        }
    }
}

extern "C" void kernel_launch(void* const* d_in, const int* in_sizes, int n_in,
                              void* d_out, int out_size, void* d_ws, size_t ws_size,
                              hipStream_t stream) {
    const float* x    = (const float*)d_in[0];
    const float* W    = (const float*)d_in[1];
    const float* bias = (const float*)d_in[2];
    const float* ew   = (const float*)d_in[3];
    const int*   erow = (const int*)d_in[4];
    const int*   ecol = (const int*)d_in[5];
    float* out = (float*)d_out;

    unsigned* ws_u = (unsigned*)d_ws;
    unsigned*        x_h4   = ws_u + XH_OFF;
    unsigned short*  x_h    = (unsigned short*)x_h4;
    unsigned short*  Wf     = (unsigned short*)(ws_u + WF_OFF);
    int*             cursor = (int*)(ws_u + CUR_OFF);
    int2*            recs   = (int2*)(ws_u + REC_OFF);

    cast_pack_zero_kernel<<<CAST_BLKS + PACK_BLKS + 1, 256, 0, stream>>>(
        x, W, x_h4, Wf, cursor);
    bin_kernel<<<NBIN, 512, 0, stream>>>(erow, ecol, ew, cursor, recs);
    agg_gemm_kernel<<<NB, 512, 0, stream>>>(x_h, recs, cursor, Wf, bias, out);
}

// Round 6
// 132.895 us; speedup vs baseline: 4.7931x; 4.7931x over previous
//
#include <hip/hip_runtime.h>
#include <hip/hip_bf16.h>

#define NN 50000
#define NE 800000
#define D 128

#define RPB 98            // rows per bucket
#define NB 511            // ceil(NN/RPB)
#define CAP 2560          // record capacity per bucket (Poisson mean 1566)
#define TILE 4096         // edges per bin block
#define NBIN 196          // ceil(NE/TILE)
#define AROWS 112         // padded rows (7 mtiles x 16)
#define TSTR 136          // bf16 tile row stride (halves); 272B, 16B-aligned

#define CAST_BLKS 3125    // 800000 uint4-casts of x
#define PACK_BLKS 8

// ws layout in dwords
#define XH_OFF   0                   // x_h bf16: 3,200,000 dwords
#define WF_OFF   3200000             // Wf: 8192 dwords
#define CUR_OFF  3208192             // 512 bucket cursors
#define REC_OFF  3208704             // records: 512*CAP int2

typedef short bf16x8 __attribute__((ext_vector_type(8)));
typedef float f32x4 __attribute__((ext_vector_type(4)));

__device__ inline unsigned short f2bf_u(float f) {
    __hip_bfloat16 h = __float2bfloat16(f);   // RNE
    return __builtin_bit_cast(unsigned short, h);
}
__device__ inline unsigned pack2(float a, float b) {
    return (unsigned)f2bf_u(a) | ((unsigned)f2bf_u(b) << 16);
}
__device__ inline void acc8(float* acc, uint4 v, float w) {
    unsigned dw[4] = {v.x, v.y, v.z, v.w};
    #pragma unroll
    for (int i = 0; i < 4; ++i) {
        float lo = __int_as_float((int)(dw[i] << 16));
        float hi = __int_as_float((int)(dw[i] & 0xffff0000u));
        acc[2 * i]     += w * lo;
        acc[2 * i + 1] += w * hi;
    }
}

// ---------------------------------------------------------------------------
// 1) fused: cast x->bf16 | pack W into MFMA-B-frag order | zero bucket cursors
// ---------------------------------------------------------------------------
__global__ __launch_bounds__(256) void cast_pack_zero_kernel(
    const float* __restrict__ x, const float* __restrict__ W,
    unsigned* __restrict__ x_h4, unsigned short* __restrict__ Wf,
    int* __restrict__ cursor)
{
    int b = blockIdx.x;
    int t = threadIdx.x;
    if (b < CAST_BLKS) {
        int idx = b * 256 + t;                 // [0, 800000)
        const float4* x4 = (const float4*)x;
        float4 v0 = x4[idx * 2];
        float4 v1 = x4[idx * 2 + 1];
        uint4 o;
        o.x = pack2(v0.x, v0.y);
        o.y = pack2(v0.z, v0.w);
        o.z = pack2(v1.x, v1.y);
        o.w = pack2(v1.z, v1.w);
        ((uint4*)x_h4)[idx] = o;
    } else if (b < CAST_BLKS + PACK_BLKS) {
        // Wf[(nt*4+c)*64+lane] : element j -> W[c*32+(lane>>4)*8+j][nt*16+(lane&15)]
        int flat = (b - CAST_BLKS) * 256 + t;  // [0, 2048)
        int lane = flat & 63;
        int c    = (flat >> 6) & 3;
        int nt   = flat >> 8;
        int col  = nt * 16 + (lane & 15);
        int kb   = c * 32 + (lane >> 4) * 8;
        unsigned d[4];
        #pragma unroll
        for (int jj = 0; jj < 4; ++jj) {
            float a  = W[(kb + 2 * jj) * D + col];
            float bb = W[(kb + 2 * jj + 1) * D + col];
            d[jj] = pack2(a, bb);
        }
        uint4 o; o.x = d[0]; o.y = d[1]; o.z = d[2]; o.w = d[3];
        ((uint4*)Wf)[flat] = o;
    } else {
        cursor[t] = 0;
        cursor[t + 256] = 0;
    }
}

// ---------------------------------------------------------------------------
// 2) bin edges into 511 coarse buckets (98 rows each); LDS staging clusters
//    the global record writes into contiguous runs. record: {(row<<16)|col, w}
//    (int LDS atomics only — native ds_add_u32, cheap)
// ---------------------------------------------------------------------------
__global__ __launch_bounds__(512) void bin_kernel(
    const int* __restrict__ erow, const int* __restrict__ ecol,
    const float* __restrict__ ew, int* __restrict__ cursor,
    int2* __restrict__ recs)
{
    __shared__ int  lhist[512];
    __shared__ int  lexcl[512];
    __shared__ int  lbase[512];
    __shared__ int2 stag[TILE];

    int t = threadIdx.x;
    int base = blockIdx.x * TILE;
    int cnt = NE - base; if (cnt > TILE) cnt = TILE;

    lhist[t] = 0;
    __syncthreads();

    int4 r[2], c[2]; float4 w[2]; bool val[2];
    #pragma unroll
    for (int g = 0; g < 2; ++g) {
        int i4 = (base >> 2) + t + g * 512;
        val[g] = (i4 * 4) < NE && (i4 * 4) < (base + TILE);
        if (val[g]) {
            r[g] = ((const int4*)erow)[i4];
            c[g] = ((const int4*)ecol)[i4];
            w[g] = ((const float4*)ew)[i4];
        }
    }
    #pragma unroll
    for (int g = 0; g < 2; ++g) {
        if (val[g]) {
            atomicAdd(&lhist[(unsigned)r[g].x / RPB], 1);
            atomicAdd(&lhist[(unsigned)r[g].y / RPB], 1);
            atomicAdd(&lhist[(unsigned)r[g].z / RPB], 1);
            atomicAdd(&lhist[(unsigned)r[g].w / RPB], 1);
        }
    }
    __syncthreads();

    int c0 = lhist[t];
    lexcl[t] = c0;
    __syncthreads();
    for (int off = 1; off < 512; off <<= 1) {
        int v = (t >= off) ? lexcl[t - off] : 0;
        __syncthreads();
        lexcl[t] += v;
        __syncthreads();
    }
    int excl = lexcl[t] - c0;
    int gb = (c0 > 0) ? atomicAdd(&cursor[t], c0) : 0;
    lexcl[t] = excl;
    lbase[t] = gb;
    lhist[t] = excl;
    __syncthreads();

    #pragma unroll
    for (int g = 0; g < 2; ++g) {
        if (val[g]) {
            int rr[4] = {r[g].x, r[g].y, r[g].z, r[g].w};
            int cc[4] = {c[g].x, c[g].y, c[g].z, c[g].w};
            float wwv[4] = {w[g].x, w[g].y, w[g].z, w[g].w};
            #pragma unroll
            for (int j = 0; j < 4; ++j) {
                int bk = (unsigned)rr[j] / RPB;
                int rank = atomicAdd(&lhist[bk], 1);
                int2 rec;
                rec.x = (rr[j] << 16) | cc[j];
                rec.y = __float_as_int(wwv[j]);
                stag[rank] = rec;
            }
        }
    }
    __syncthreads();

    #pragma unroll
    for (int k = 0; k < 8; ++k) {
        int i = t + k * 512;
        if (i < cnt) {
            int2 rec = stag[i];
            int row = ((unsigned)rec.x) >> 16;
            int bk = (unsigned)row / RPB;
            size_t g = (size_t)bk * CAP + lbase[bk] + (i - lexcl[bk]);
            recs[g] = rec;
        }
    }
}

// ---------------------------------------------------------------------------
// 3) per-bucket: counting-sort records by row in LDS -> register-accumulating
//    gather (16 lanes/node) -> bf16 LDS tile -> MFMA GEMM + bias -> out.
//    No float atomics anywhere.
// ---------------------------------------------------------------------------
__global__ __launch_bounds__(512) void gat_gemm_kernel(
    const unsigned short* __restrict__ x_h, const int2* __restrict__ recs,
    const int* __restrict__ cursor, const unsigned short* __restrict__ Wf,
    const float* __restrict__ bias, float* __restrict__ out)
{
    __shared__ int2 srec[CAP];                          // 20 KB
    __shared__ __align__(16) unsigned short tile[AROWS * TSTR];  // 30.5 KB
    __shared__ int rowstart[RPB + 1];
    __shared__ int rowcur[RPB];
    __shared__ int stmp[128];

    int t = threadIdx.x;
    int b = blockIdx.x;
    int cnt = cursor[b];
    int rb = b * RPB;
    const int2* my = recs + (size_t)b * CAP;

    if (t < RPB) rowcur[t] = 0;
    __syncthreads();

    // pass 1: row histogram (int ds_add)
    for (int i = t; i < cnt; i += 512) {
        int2 rec = my[i];
        atomicAdd(&rowcur[(((unsigned)rec.x) >> 16) - rb], 1);
    }
    __syncthreads();

    // exclusive scan of 98 counts (first 128 threads, Hillis-Steele)
    int myv = 0;
    if (t < 128) { myv = (t < RPB) ? rowcur[t] : 0; stmp[t] = myv; }
    __syncthreads();
    for (int off = 1; off < 128; off <<= 1) {
        int v = 0;
        if (t < 128 && t >= off) v = stmp[t - off];
        __syncthreads();
        if (t < 128) stmp[t] += v;
        __syncthreads();
    }
    if (t < RPB) { int ex = stmp[t] - myv; rowstart[t] = ex; rowcur[t] = ex; }
    if (t == 0) rowstart[RPB] = cnt;
    __syncthreads();

    // pass 2: rank + scatter into srec (sorted by row)
    for (int i = t; i < cnt; i += 512) {
        int2 rec = my[i];
        int rl = (((unsigned)rec.x) >> 16) - rb;
        int rank = atomicAdd(&rowcur[rl], 1);
        srec[rank] = rec;
    }
    __syncthreads();

    // gather: 16 lanes per node, 32 nodes concurrently, register accumulation
    int q = t & 15;
    int grp = t >> 4;
    const uint4* xv = (const uint4*)x_h;   // one x row = 16 uint4
    #pragma unroll
    for (int it = 0; it < 4; ++it) {
        int rl = it * 32 + grp;
        if (rl < RPB) {
            int p = rowstart[rl], p1 = rowstart[rl + 1];
            float acc[8] = {};
            for (; p + 2 <= p1; p += 2) {
                int2 e0 = srec[p];
                int2 e1 = srec[p + 1];
                uint4 v0 = xv[(size_t)(e0.x & 0xffff) * 16 + q];
                uint4 v1 = xv[(size_t)(e1.x & 0xffff) * 16 + q];
                acc8(acc, v0, __int_as_float(e0.y));
                acc8(acc, v1, __int_as_float(e1.y));
            }
            if (p < p1) {
                int2 e = srec[p];
                uint4 v = xv[(size_t)(e.x & 0xffff) * 16 + q];
                acc8(acc, v, __int_as_float(e.y));
            }
            uint4 o;
            o.x = pack2(acc[0], acc[1]);
            o.y = pack2(acc[2], acc[3]);
            o.z = pack2(acc[4], acc[5]);
            o.w = pack2(acc[6], acc[7]);
            *(uint4*)&tile[rl * TSTR + q * 8] = o;
        }
    }
    __syncthreads();

    // MFMA tail: wave = ntile (8 waves x 16 cols); rows 98..111 are garbage
    // but D[m][*] depends only on A row m, and stores are guarded.
    int wave = t >> 6, lane = t & 63;
    int m = lane & 15, quad = lane >> 4;
    const bf16x8* bp = (const bf16x8*)Wf;
    bf16x8 bfr[4];
    #pragma unroll
    for (int c = 0; c < 4; ++c) bfr[c] = bp[(wave * 4 + c) * 64 + lane];
    float bcol = bias[wave * 16 + m];

    #pragma unroll
    for (int mt = 0; mt < 7; ++mt) {
        f32x4 acc = {0.f, 0.f, 0.f, 0.f};
        #pragma unroll
        for (int c = 0; c < 4; ++c) {
            bf16x8 afr = *(const bf16x8*)&tile[(mt * 16 + m) * TSTR + c * 32 + quad * 8];
            acc = __builtin_amdgcn_mfma_f32_16x16x32_bf16(afr, bfr[c], acc, 0, 0, 0);
        }
        #pragma unroll
        for (int r = 0; r < 4; ++r) {
            int lr = mt * 16 + quad * 4 + r;
            int grow = rb + lr;
            if (lr < RPB && grow < NN)
                out[(size_t)grow * D + wave * 16 + m] = acc[r] + bcol;
        }
    }
}

extern "C" void kernel_launch(void* const* d_in, const int* in_sizes, int n_in,
                              void* d_out, int out_size, void* d_ws, size_t ws_size,
                              hipStream_t stream) {
    const float* x    = (const float*)d_in[0];
    const float* W    = (const float*)d_in[1];
    const float* bias = (const float*)d_in[2];
    const float* ew   = (const float*)d_in[3];
    const int*   erow = (const int*)d_in[4];
    const int*   ecol = (const int*)d_in[5];
    float* out = (float*)d_out;

    unsigned* ws_u = (unsigned*)d_ws;
    unsigned*        x_h4   = ws_u + XH_OFF;
    unsigned short*  x_h    = (unsigned short*)x_h4;
    unsigned short*  Wf     = (unsigned short*)(ws_u + WF_OFF);
    int*             cursor = (int*)(ws_u + CUR_OFF);
    int2*            recs   = (int2*)(ws_u + REC_OFF);

    cast_pack_zero_kernel<<<CAST_BLKS + PACK_BLKS + 1, 256, 0, stream>>>(
        x, W, x_h4, Wf, cursor);
    bin_kernel<<<NBIN, 512, 0, stream>>>(erow, ecol, ew, cursor, recs);
    gat_gemm_kernel<<<NB, 512, 0, stream>>>(x_h, recs, cursor, Wf, bias, out);
}

// Round 7
// 129.831 us; speedup vs baseline: 4.9062x; 1.0236x over previous
//
#include <hip/hip_runtime.h>
#include <hip/hip_bf16.h>

#define NN 50000
#define NE 800000
#define D 128

#define RPB 50            // rows per bucket
#define NB 1000           // NN / RPB
#define NBP 1024          // padded bin count (LDS/scan)
#define CAP 1024          // record capacity per bucket (mean 800, +8 sigma)
#define TILE 4096         // edges per bin block
#define NBIN 196          // ceil(NE/TILE)
#define AROWS 64          // padded rows (4 mtiles x 16)
#define TSTR 136          // bf16 tile row stride (halves): 272B, 16B-aligned, banks+4

#define CASTB 1563        // ceil(800000 / 512) uint4-casts of x
#define PACKB 4           // 2048 threads / 512

// ws layout in dwords
#define XH_OFF   0                   // x_h bf16: 3,200,000 dwords
#define WF_OFF   3200000             // Wf: 8192 dwords
#define CUR_OFF  3208192             // NBP cursors
#define REC_OFF  3209216             // records: NB*CAP int2 = 2,048,000 dwords

typedef short bf16x8 __attribute__((ext_vector_type(8)));
typedef float f32x4 __attribute__((ext_vector_type(4)));

__device__ inline unsigned short f2bf_u(float f) {
    __hip_bfloat16 h = __float2bfloat16(f);   // RNE
    return __builtin_bit_cast(unsigned short, h);
}
__device__ inline unsigned pack2(float a, float b) {
    return (unsigned)f2bf_u(a) | ((unsigned)f2bf_u(b) << 16);
}
__device__ inline void acc8(float* acc, uint4 v, float w) {
    unsigned dw[4] = {v.x, v.y, v.z, v.w};
    #pragma unroll
    for (int i = 0; i < 4; ++i) {
        float lo = __int_as_float((int)(dw[i] << 16));
        float hi = __int_as_float((int)(dw[i] & 0xffff0000u));
        acc[2 * i]     += w * lo;
        acc[2 * i + 1] += w * hi;
    }
}

// ---------------------------------------------------------------------------
// 1) fused grid: [0,CASTB) cast x->bf16 | [..+PACKB) pack W B-frag |
//    [..+NBIN) bin edges into 1000 coarse buckets via LDS staging.
//    cursor[] zeroed by a prior hipMemsetAsync.
// ---------------------------------------------------------------------------
__global__ __launch_bounds__(512) void cast_bin_kernel(
    const float* __restrict__ x, const float* __restrict__ W,
    const int* __restrict__ erow, const int* __restrict__ ecol,
    const float* __restrict__ ew,
    unsigned* __restrict__ x_h4, unsigned short* __restrict__ Wf,
    int* __restrict__ cursor, int2* __restrict__ recs)
{
    __shared__ int  lhist[NBP];
    __shared__ int  lexcl[NBP];
    __shared__ int  lbase[NBP];
    __shared__ int  lpair[512];
    __shared__ int2 stag[TILE];

    int b = blockIdx.x;
    int t = threadIdx.x;

    if (b < CASTB) {
        int idx = b * 512 + t;                 // [0, 800000)
        if (idx < 800000) {
            const float4* x4 = (const float4*)x;
            float4 v0 = x4[idx * 2];
            float4 v1 = x4[idx * 2 + 1];
            uint4 o;
            o.x = pack2(v0.x, v0.y);
            o.y = pack2(v0.z, v0.w);
            o.z = pack2(v1.x, v1.y);
            o.w = pack2(v1.z, v1.w);
            ((uint4*)x_h4)[idx] = o;
        }
        return;
    }
    if (b < CASTB + PACKB) {
        // Wf[(nt*4+c)*64+lane] : element j -> W[c*32+(lane>>4)*8+j][nt*16+(lane&15)]
        int flat = (b - CASTB) * 512 + t;      // [0, 2048)
        int lane = flat & 63;
        int c    = (flat >> 6) & 3;
        int nt   = flat >> 8;
        int col  = nt * 16 + (lane & 15);
        int kb   = c * 32 + (lane >> 4) * 8;
        unsigned d[4];
        #pragma unroll
        for (int jj = 0; jj < 4; ++jj) {
            float a  = W[(kb + 2 * jj) * D + col];
            float bb = W[(kb + 2 * jj + 1) * D + col];
            d[jj] = pack2(a, bb);
        }
        uint4 o; o.x = d[0]; o.y = d[1]; o.z = d[2]; o.w = d[3];
        ((uint4*)Wf)[flat] = o;
        return;
    }

    // ---- bin branch ----
    int base = (b - CASTB - PACKB) * TILE;
    int cnt = NE - base; if (cnt > TILE) cnt = TILE;

    lhist[t] = 0;
    lhist[t + 512] = 0;
    __syncthreads();

    int4 r[2], c[2]; float4 w[2]; bool val[2];
    #pragma unroll
    for (int g = 0; g < 2; ++g) {
        int i4 = (base >> 2) + t + g * 512;
        val[g] = (i4 * 4) < NE && (i4 * 4) < (base + TILE);
        if (val[g]) {
            r[g] = ((const int4*)erow)[i4];
            c[g] = ((const int4*)ecol)[i4];
            w[g] = ((const float4*)ew)[i4];
        }
    }
    #pragma unroll
    for (int g = 0; g < 2; ++g) {
        if (val[g]) {
            atomicAdd(&lhist[(unsigned)r[g].x / RPB], 1);
            atomicAdd(&lhist[(unsigned)r[g].y / RPB], 1);
            atomicAdd(&lhist[(unsigned)r[g].z / RPB], 1);
            atomicAdd(&lhist[(unsigned)r[g].w / RPB], 1);
        }
    }
    __syncthreads();

    // scan 1024 bins with 512 threads (pair-sum + Hillis-Steele)
    int a0 = lhist[2 * t], a1 = lhist[2 * t + 1];
    lpair[t] = a0 + a1;
    __syncthreads();
    for (int off = 1; off < 512; off <<= 1) {
        int v = (t >= off) ? lpair[t - off] : 0;
        __syncthreads();
        lpair[t] += v;
        __syncthreads();
    }
    int exclp = lpair[t] - (a0 + a1);
    lexcl[2 * t]     = exclp;
    lexcl[2 * t + 1] = exclp + a0;
    lbase[2 * t]     = a0 ? atomicAdd(&cursor[2 * t], a0) : 0;
    lbase[2 * t + 1] = a1 ? atomicAdd(&cursor[2 * t + 1], a1) : 0;
    lhist[2 * t]     = exclp;          // rank cursor
    lhist[2 * t + 1] = exclp + a0;
    __syncthreads();

    #pragma unroll
    for (int g = 0; g < 2; ++g) {
        if (val[g]) {
            int rr[4] = {r[g].x, r[g].y, r[g].z, r[g].w};
            int cc[4] = {c[g].x, c[g].y, c[g].z, c[g].w};
            float wwv[4] = {w[g].x, w[g].y, w[g].z, w[g].w};
            #pragma unroll
            for (int j = 0; j < 4; ++j) {
                int bk = (unsigned)rr[j] / RPB;
                int rank = atomicAdd(&lhist[bk], 1);
                int2 rec;
                rec.x = (rr[j] << 16) | cc[j];
                rec.y = __float_as_int(wwv[j]);
                stag[rank] = rec;
            }
        }
    }
    __syncthreads();

    #pragma unroll
    for (int k = 0; k < 8; ++k) {
        int i = t + k * 512;
        if (i < cnt) {
            int2 rec = stag[i];
            int bk = (((unsigned)rec.x) >> 16) / RPB;
            int pos = lbase[bk] + (i - lexcl[bk]);
            if (pos < CAP)
                recs[(size_t)bk * CAP + pos] = rec;
        }
    }
}

// ---------------------------------------------------------------------------
// 2) per-bucket (50 rows): single global pass of records into registers ->
//    LDS counting-sort by row -> register gather (16 lanes/node) ->
//    bf16 LDS tile -> MFMA GEMM + bias -> out. No float atomics.
// ---------------------------------------------------------------------------
__global__ __launch_bounds__(512) void gat_gemm_kernel(
    const unsigned short* __restrict__ x_h, const int2* __restrict__ recs,
    const int* __restrict__ cursor, const unsigned short* __restrict__ Wf,
    const float* __restrict__ bias, float* __restrict__ out)
{
    __shared__ int2 srec[CAP];                                   // 8 KB
    __shared__ __align__(16) unsigned short tile[AROWS * TSTR];  // 17.4 KB
    __shared__ int rowstart[RPB + 1];
    __shared__ int rowcur[64];
    __shared__ int stmp[64];

    int t = threadIdx.x;
    int b = blockIdx.x;
    int cnt = cursor[b];
    if (cnt > CAP) cnt = CAP;
    int rb = b * RPB;
    const int2* my = recs + (size_t)b * CAP;

    if (t < 64) rowcur[t] = 0;
    __syncthreads();

    // single global pass: records -> registers
    int2 r0, r1;
    bool v0 = t < cnt, v1 = t + 512 < cnt;
    if (v0) r0 = my[t];
    if (v1) r1 = my[t + 512];

    if (v0) atomicAdd(&rowcur[(((unsigned)r0.x) >> 16) - rb], 1);
    if (v1) atomicAdd(&rowcur[(((unsigned)r1.x) >> 16) - rb], 1);
    __syncthreads();

    // exclusive scan of 50 row counts (first 64 threads)
    int myc = 0;
    if (t < 64) { myc = rowcur[t]; stmp[t] = myc; }
    __syncthreads();
    for (int off = 1; off < 64; off <<= 1) {
        int v = 0;
        if (t < 64 && t >= off) v = stmp[t - off];
        __syncthreads();
        if (t < 64) stmp[t] += v;
        __syncthreads();
    }
    if (t < 64) { int ex = stmp[t] - myc; if (t <= RPB) rowstart[t] = ex; rowcur[t] = ex; }
    if (t == 0) rowstart[RPB] = cnt;
    __syncthreads();

    // rank + scatter into srec (sorted by row)
    if (v0) srec[atomicAdd(&rowcur[(((unsigned)r0.x) >> 16) - rb], 1)] = r0;
    if (v1) srec[atomicAdd(&rowcur[(((unsigned)r1.x) >> 16) - rb], 1)] = r1;
    __syncthreads();

    // gather: 16 lanes per node, 32 nodes concurrently, unroll 4
    int q = t & 15;
    int grp = t >> 4;
    const uint4* xv = (const uint4*)x_h;   // one x row = 16 uint4
    #pragma unroll
    for (int it = 0; it < 2; ++it) {
        int rl = it * 32 + grp;
        if (rl < RPB) {
            int p = rowstart[rl], p1 = rowstart[rl + 1];
            float acc[8] = {};
            for (; p + 4 <= p1; p += 4) {
                int2 e0 = srec[p];
                int2 e1 = srec[p + 1];
                int2 e2 = srec[p + 2];
                int2 e3 = srec[p + 3];
                uint4 w0 = xv[(size_t)(e0.x & 0xffff) * 16 + q];
                uint4 w1 = xv[(size_t)(e1.x & 0xffff) * 16 + q];
                uint4 w2 = xv[(size_t)(e2.x & 0xffff) * 16 + q];
                uint4 w3 = xv[(size_t)(e3.x & 0xffff) * 16 + q];
                acc8(acc, w0, __int_as_float(e0.y));
                acc8(acc, w1, __int_as_float(e1.y));
                acc8(acc, w2, __int_as_float(e2.y));
                acc8(acc, w3, __int_as_float(e3.y));
            }
            for (; p < p1; ++p) {
                int2 e = srec[p];
                uint4 w = xv[(size_t)(e.x & 0xffff) * 16 + q];
                acc8(acc, w, __int_as_float(e.y));
            }
            uint4 o;
            o.x = pack2(acc[0], acc[1]);
            o.y = pack2(acc[2], acc[3]);
            o.z = pack2(acc[4], acc[5]);
            o.w = pack2(acc[6], acc[7]);
            *(uint4*)&tile[rl * TSTR + q * 8] = o;
        }
    }
    __syncthreads();

    // MFMA tail: 8 waves x (16-col ntile); rows 50..63 garbage but D row m
    // depends only on A row m; stores guarded.
    int wave = t >> 6, lane = t & 63;
    int m = lane & 15, quad = lane >> 4;
    const bf16x8* bp = (const bf16x8*)Wf;
    bf16x8 bfr[4];
    #pragma unroll
    for (int c = 0; c < 4; ++c) bfr[c] = bp[(wave * 4 + c) * 64 + lane];
    float bcol = bias[wave * 16 + m];

    #pragma unroll
    for (int mt = 0; mt < 4; ++mt) {
        f32x4 acc = {0.f, 0.f, 0.f, 0.f};
        #pragma unroll
        for (int c = 0; c < 4; ++c) {
            bf16x8 afr = *(const bf16x8*)&tile[(mt * 16 + m) * TSTR + c * 32 + quad * 8];
            acc = __builtin_amdgcn_mfma_f32_16x16x32_bf16(afr, bfr[c], acc, 0, 0, 0);
        }
        #pragma unroll
        for (int r = 0; r < 4; ++r) {
            int lr = mt * 16 + quad * 4 + r;
            int grow = rb + lr;
            if (lr < RPB && grow < NN)
                out[(size_t)grow * D + wave * 16 + m] = acc[r] + bcol;
        }
    }
}

extern "C" void kernel_launch(void* const* d_in, const int* in_sizes, int n_in,
                              void* d_out, int out_size, void* d_ws, size_t ws_size,
                              hipStream_t stream) {
    const float* x    = (const float*)d_in[0];
    const float* W    = (const float*)d_in[1];
    const float* bias = (const float*)d_in[2];
    const float* ew   = (const float*)d_in[3];
    const int*   erow = (const int*)d_in[4];
    const int*   ecol = (const int*)d_in[5];
    float* out = (float*)d_out;

    unsigned* ws_u = (unsigned*)d_ws;
    unsigned*        x_h4   = ws_u + XH_OFF;
    unsigned short*  x_h    = (unsigned short*)x_h4;
    unsigned short*  Wf     = (unsigned short*)(ws_u + WF_OFF);
    int*             cursor = (int*)(ws_u + CUR_OFF);
    int2*            recs   = (int2*)(ws_u + REC_OFF);

    hipMemsetAsync(cursor, 0, NBP * sizeof(int), stream);
    cast_bin_kernel<<<CASTB + PACKB + NBIN, 512, 0, stream>>>(
        x, W, erow, ecol, ew, x_h4, Wf, cursor, recs);
    gat_gemm_kernel<<<NB, 512, 0, stream>>>(x_h, recs, cursor, Wf, bias, out);
}